// Round 2
// baseline (192.431 us; speedup 1.0000x reference)
//
#include <hip/hip_runtime.h>
#include <hip/hip_bf16.h>

#define NN 20000
#define GG 128

typedef __bf16 bf16x8_t __attribute__((ext_vector_type(8)));
typedef float  f32x4_t  __attribute__((ext_vector_type(4)));
typedef __hip_bfloat16 hbf16;

// packed-weight table in ws (bf16-element offsets)
#define PK_NPW1 0       // 32768 : npW1 B-frags (16 ct x 4 kb x 64 lane x 8)
#define PK_PPW1 32768   // 16384 : ppW1 (8 ct x 4 kb x 64 x 8)
#define PK_NPW2 49152   //  4096 : npW2 (8 kb x 64 x 8), cols>=12 zero
#define PK_PPW2 53248   //  2048 : ppW2 (4 kb x 64 x 8), cols>=3 zero
#define PK_WN   55296   //  4096 : Wn   (8 ct x 64 x 8), K padded 12->32
#define GADD_OFF 59392  // then gadd fp32[128][128]

__device__ __forceinline__ float silu_f(float v) {
    return v * __builtin_amdgcn_rcpf(1.0f + __expf(-v));
}

// ---------------------------------------------------------------------------
// Kernel 1: blocks [0,128): per-graph gadd pipeline (512 thr, deep split-k).
//           blocks [128,244): pack weights into MFMA B-fragment order.
// (unchanged from verified version)
// ---------------------------------------------------------------------------
__global__ __launch_bounds__(512) void prep_kernel(
        const float* __restrict__ t, const float* __restrict__ topo,
        const float* __restrict__ stab, const float* __restrict__ sust,
        const float* __restrict__ tmW1, const float* __restrict__ tmb1,
        const float* __restrict__ tmW2, const float* __restrict__ tmb2,
        const float* __restrict__ topoW1, const float* __restrict__ topob1,
        const float* __restrict__ topoW2, const float* __restrict__ topob2,
        const float* __restrict__ stabW1, const float* __restrict__ stabb1,
        const float* __restrict__ stabW2, const float* __restrict__ stabb2,
        const float* __restrict__ sustW1, const float* __restrict__ sustb1,
        const float* __restrict__ sustW2, const float* __restrict__ sustb2,
        const float* __restrict__ combW1, const float* __restrict__ combb1,
        const float* __restrict__ combW2, const float* __restrict__ combb2,
        const float* __restrict__ Wv, const float* __restrict__ Wo,
        const float* __restrict__ bo,
        const float* __restrict__ npW1, const float* __restrict__ npW2,
        const float* __restrict__ ppW1, const float* __restrict__ ppW2,
        const float* __restrict__ Wn,
        float* __restrict__ gadd, hbf16* __restrict__ wsb) {
    const int tid = threadIdx.x;

    if (blockIdx.x >= GG) {
        const int s = (blockIdx.x - GG) * 512 + tid;
        if (s < 32768) {                       // npW1: [128,256]
            const int p = s;
            const int j = p & 7, l = (p >> 3) & 63, kb = (p >> 9) & 3, ct = p >> 11;
            const int k = kb * 32 + ((l >> 4) << 3) + j;
            const int n = ct * 16 + (l & 15);
            wsb[PK_NPW1 + p] = __float2bfloat16(npW1[k * 256 + n]);
        } else if (s < 49152) {                // ppW1: [128,128]
            const int p = s - 32768;
            const int j = p & 7, l = (p >> 3) & 63, kb = (p >> 9) & 3, ct = p >> 11;
            const int k = kb * 32 + ((l >> 4) << 3) + j;
            const int n = ct * 16 + (l & 15);
            wsb[PK_PPW1 + p] = __float2bfloat16(ppW1[k * 128 + n]);
        } else if (s < 53248) {                // npW2: [256,12] -> N padded 16
            const int p = s - 49152;
            const int j = p & 7, l = (p >> 3) & 63, kb = p >> 9;
            const int k = kb * 32 + ((l >> 4) << 3) + j;
            const int n = l & 15;
            wsb[PK_NPW2 + p] = __float2bfloat16(n < 12 ? npW2[k * 12 + n] : 0.0f);
        } else if (s < 55296) {                // ppW2: [128,3] -> N padded 16
            const int p = s - 53248;
            const int j = p & 7, l = (p >> 3) & 63, kb = p >> 9;
            const int k = kb * 32 + ((l >> 4) << 3) + j;
            const int n = l & 15;
            wsb[PK_PPW2 + p] = __float2bfloat16(n < 3 ? ppW2[k * 3 + n] : 0.0f);
        } else if (s < 59392) {                // Wn: [12,128] -> K padded 32
            const int p = s - 55296;
            const int j = p & 7, l = (p >> 3) & 63, ct = p >> 9;
            const int k = ((l >> 4) << 3) + j;
            const int n = ct * 16 + (l & 15);
            wsb[PK_WN + p] = __float2bfloat16(k < 12 ? Wn[k * 128 + n] : 0.0f);
        }
        return;
    }

    __shared__ float s_te[128];
    __shared__ float s_th1[256];
    __shared__ float s_tef[128];
    __shared__ float s_l1[64];
    __shared__ float s_cat[64];
    __shared__ float s_c1[64];
    __shared__ float s_cond[64];
    __shared__ float s_v[128];
    __shared__ float s_red[512];

    const int g = blockIdx.x;

    if (tid < 128) {
        const float tval = t[g];
        const int i = tid & 63;
        const float fr = __expf(-(float)i * 0.14619587892025688f);
        const float arg = tval * fr;
        s_te[tid] = (tid < 64) ? sinf(arg) : cosf(arg);
    } else if (tid < 192) {
        const int c = tid - 128;
        if (c < 32) {
            float acc = topob1[c];
            for (int k = 0; k < 7; ++k)
                acc += topo[g * 7 + k] * topoW1[k * 32 + c];
            s_l1[c] = silu_f(acc);
        } else if (c < 48) {
            const int j = c - 32;
            float acc = stabb1[j];
            for (int k = 0; k < 2; ++k)
                acc += stab[g * 2 + k] * stabW1[k * 16 + j];
            s_l1[c] = silu_f(acc);
        } else {
            const int j = c - 48;
            float acc = sustb1[j];
            for (int k = 0; k < 3; ++k)
                acc += sust[g * 3 + k] * sustW1[k * 16 + j];
            s_l1[c] = silu_f(acc);
        }
    }
    __syncthreads();

    // tmW1 [128]->[256]: split-k 2
    {
        const int col = tid & 255, half = tid >> 8;
        float acc = 0.0f;
#pragma unroll 32
        for (int kk = 0; kk < 64; ++kk) {
            const int k = half * 64 + kk;
            acc += s_te[k] * tmW1[k * 256 + col];
        }
        s_red[half * 256 + col] = acc;
    }
    __syncthreads();
    if (tid < 256)
        s_th1[tid] = silu_f(tmb1[tid] + s_red[tid] + s_red[256 + tid]);
    __syncthreads();

    // tmW2 [256]->[128]: split-k 4
    {
        const int col = tid & 127, qt = tid >> 7;
        float acc = 0.0f;
#pragma unroll 32
        for (int kk = 0; kk < 64; ++kk) {
            const int k = qt * 64 + kk;
            acc += s_th1[k] * tmW2[k * 128 + col];
        }
        s_red[qt * 128 + col] = acc;
    }
    __syncthreads();
    if (tid < 128) {
        s_tef[tid] = tmb2[tid] + s_red[tid] + s_red[128 + tid] +
                     s_red[256 + tid] + s_red[384 + tid];
    } else if (tid < 192) {
        const int c = tid - 128;
        if (c < 32) {
            float acc = topob2[c];
            for (int k = 0; k < 32; ++k)
                acc += s_l1[k] * topoW2[k * 32 + c];
            s_cat[c] = acc;
        } else if (c < 48) {
            const int j = c - 32;
            float acc = stabb2[j];
            for (int k = 0; k < 16; ++k)
                acc += s_l1[32 + k] * stabW2[k * 16 + j];
            s_cat[c] = acc;
        } else {
            const int j = c - 48;
            float acc = sustb2[j];
            for (int k = 0; k < 16; ++k)
                acc += s_l1[48 + k] * sustW2[k * 16 + j];
            s_cat[c] = acc;
        }
    }
    __syncthreads();

    // comb L1: split-k 8
    {
        const int col = tid & 63, part = tid >> 6;
        float acc = 0.0f;
#pragma unroll
        for (int kk = 0; kk < 8; ++kk) {
            const int k = part * 8 + kk;
            acc += s_cat[k] * combW1[k * 64 + col];
        }
        s_red[part * 64 + col] = acc;
    }
    __syncthreads();
    if (tid < 64) {
        float a = combb1[tid];
#pragma unroll
        for (int p = 0; p < 8; ++p) a += s_red[p * 64 + tid];
        s_c1[tid] = silu_f(a);
    }
    __syncthreads();

    // comb L2: split-k 8
    {
        const int col = tid & 63, part = tid >> 6;
        float acc = 0.0f;
#pragma unroll
        for (int kk = 0; kk < 8; ++kk) {
            const int k = part * 8 + kk;
            acc += s_c1[k] * combW2[k * 64 + col];
        }
        s_red[part * 64 + col] = acc;
    }
    __syncthreads();
    if (tid < 64) {
        float a = combb2[tid];
#pragma unroll
        for (int p = 0; p < 8; ++p) a += s_red[p * 64 + tid];
        s_cond[tid] = a;
    }
    __syncthreads();

    // v = cond @ Wv: split-k 4
    {
        const int col = tid & 127, qt = tid >> 7;
        float acc = 0.0f;
#pragma unroll
        for (int kk = 0; kk < 16; ++kk) {
            const int k = qt * 16 + kk;
            acc += s_cond[k] * Wv[k * 128 + col];
        }
        s_red[qt * 128 + col] = acc;
    }
    __syncthreads();
    if (tid < 128)
        s_v[tid] = s_red[tid] + s_red[128 + tid] + s_red[256 + tid] + s_red[384 + tid];
    __syncthreads();

    // a = v @ Wo: split-k 4 ; gadd = 6*(a + bo + silu(tef))
    {
        const int col = tid & 127, qt = tid >> 7;
        float acc = 0.0f;
#pragma unroll 32
        for (int kk = 0; kk < 32; ++kk) {
            const int k = qt * 32 + kk;
            acc += s_v[k] * Wo[k * 128 + col];
        }
        s_red[qt * 128 + col] = acc;
    }
    __syncthreads();
    if (tid < 128)
        gadd[g * 128 + tid] = 6.0f * (bo[tid] + s_red[tid] + s_red[128 + tid] +
                                      s_red[256 + tid] + s_red[384 + tid] +
                                      silu_f(s_tef[tid]));
}

// ---------------------------------------------------------------------------
// Kernel 2: per-node MLPs.  One wave per block, 32 nodes per wave as TWO
// M=16 tiles (20000 = 625 * 32 exactly, no tail).  Each B-fragment is loaded
// ONCE from the packed L2-resident global table and feeds BOTH tiles' MFMA
// chains: halves L2 weight traffic (145 -> 72 MB) and doubles MFMA ILP per
// load.  No LDS weight staging, no cross-wave sharing.
// MFMA contract (16x16x32 bf16), q=lane>>4, r=lane&15:
//   A[m=r][k=q*8+j]   B[k=q*8+j][n=r]   D[m=q*4+i][n=r]
// LDS: two per-tile transpose buffers (16.5 KB).  __syncthreads() are
// single-wave (cheap) and order the cross-lane LDS hazards between phases.
// ---------------------------------------------------------------------------
__global__ __launch_bounds__(64) void node_kernel(
        const float* __restrict__ x, const int* __restrict__ batch,
        const float* __restrict__ bn,
        const float* __restrict__ npb1, const float* __restrict__ npb2,
        const float* __restrict__ ppb1, const float* __restrict__ ppb2,
        const float* __restrict__ gadd, const hbf16* __restrict__ wsb,
        float* __restrict__ out) {
    __shared__ __align__(16) hbf16 wb[2][16 * 264];   // 16.5 KB, single wave

    const int lane = threadIdx.x;
    const int q    = lane >> 4;
    const int r    = lane & 15;
    const int n32  = blockIdx.x * 32;

    // x A-frags (M=16 each, K=12 padded to 32), tiles 0/1
    bf16x8_t Ax[2];
#pragma unroll
    for (int tt = 0; tt < 2; ++tt) {
        const int node = n32 + tt * 16 + r;    // always < NN (exact tiling)
        float xv[8];
#pragma unroll
        for (int j = 0; j < 8; ++j) xv[j] = 0.0f;
        if (q == 0) {
            const float4 a = *reinterpret_cast<const float4*>(x + node * 12);
            const float4 b = *reinterpret_cast<const float4*>(x + node * 12 + 4);
            xv[0] = a.x; xv[1] = a.y; xv[2] = a.z; xv[3] = a.w;
            xv[4] = b.x; xv[5] = b.y; xv[6] = b.z; xv[7] = b.w;
        } else if (q == 1) {
            const float4 a = *reinterpret_cast<const float4*>(x + node * 12 + 8);
            xv[0] = a.x; xv[1] = a.y; xv[2] = a.z; xv[3] = a.w;
        }
#pragma unroll
        for (int j = 0; j < 8; ++j) {
            const hbf16 tv = __float2bfloat16(xv[j]);
            Ax[tt][j] = *reinterpret_cast<const __bf16*>(&tv);
        }
    }
    // graph id per output row (D rows m = q*4+i), per tile
    int gb[2][4];
#pragma unroll
    for (int tt = 0; tt < 2; ++tt)
#pragma unroll
        for (int i = 0; i < 4; ++i)
            gb[tt][i] = batch[n32 + tt * 16 + q * 4 + i];

    // ---- h = x@Wn + bn + gadd  -> wb[tt] stride 136 ; Ah regs
    bf16x8_t Ah[2][4];
#pragma unroll
    for (int ct = 0; ct < 8; ++ct) {
        const bf16x8_t Bf = *reinterpret_cast<const bf16x8_t*>(
            &wsb[PK_WN + (ct * 64 + lane) * 8]);
        const f32x4_t a0 = __builtin_amdgcn_mfma_f32_16x16x32_bf16(
            Ax[0], Bf, (f32x4_t){0.f, 0.f, 0.f, 0.f}, 0, 0, 0);
        const f32x4_t a1 = __builtin_amdgcn_mfma_f32_16x16x32_bf16(
            Ax[1], Bf, (f32x4_t){0.f, 0.f, 0.f, 0.f}, 0, 0, 0);
        const int n = ct * 16 + r;
        const float bv = bn[n];
#pragma unroll
        for (int i = 0; i < 4; ++i)
            wb[0][(q * 4 + i) * 136 + n] = __float2bfloat16(
                a0[i] + bv + gadd[gb[0][i] * 128 + n]);
#pragma unroll
        for (int i = 0; i < 4; ++i)
            wb[1][(q * 4 + i) * 136 + n] = __float2bfloat16(
                a1[i] + bv + gadd[gb[1][i] * 128 + n]);
    }
    __syncthreads();    // order h writes (all lanes) before Ah frag reads
#pragma unroll
    for (int tt = 0; tt < 2; ++tt)
#pragma unroll
        for (int kb = 0; kb < 4; ++kb)
            Ah[tt][kb] = *reinterpret_cast<const bf16x8_t*>(
                &wb[tt][r * 136 + kb * 32 + q * 8]);

    // ---- np L1: z1 = silu(h@npW1 + b1) -> wb stride 264  (K=256)
#pragma unroll
    for (int ct = 0; ct < 16; ++ct) {
        f32x4_t a0 = (f32x4_t){0.f, 0.f, 0.f, 0.f};
        f32x4_t a1 = (f32x4_t){0.f, 0.f, 0.f, 0.f};
#pragma unroll
        for (int kb = 0; kb < 4; ++kb) {
            const bf16x8_t Bf = *reinterpret_cast<const bf16x8_t*>(
                &wsb[PK_NPW1 + ((ct * 4 + kb) * 64 + lane) * 8]);
            a0 = __builtin_amdgcn_mfma_f32_16x16x32_bf16(Ah[0][kb], Bf, a0, 0, 0, 0);
            a1 = __builtin_amdgcn_mfma_f32_16x16x32_bf16(Ah[1][kb], Bf, a1, 0, 0, 0);
        }
        const int col = ct * 16 + r;
        const float b1 = npb1[col];
#pragma unroll
        for (int i = 0; i < 4; ++i)
            wb[0][(q * 4 + i) * 264 + col] = __float2bfloat16(silu_f(a0[i] + b1));
#pragma unroll
        for (int i = 0; i < 4; ++i)
            wb[1][(q * 4 + i) * 264 + col] = __float2bfloat16(silu_f(a1[i] + b1));
    }
    __syncthreads();    // z1 writes before np L2 frag reads

    // ---- np L2: out12 = z1 @ npW2 + b2
    {
        f32x4_t c0 = (f32x4_t){0.f, 0.f, 0.f, 0.f};
        f32x4_t c1 = (f32x4_t){0.f, 0.f, 0.f, 0.f};
#pragma unroll
        for (int kb = 0; kb < 8; ++kb) {
            const bf16x8_t Bf = *reinterpret_cast<const bf16x8_t*>(
                &wsb[PK_NPW2 + (kb * 64 + lane) * 8]);
            const bf16x8_t Af0 = *reinterpret_cast<const bf16x8_t*>(
                &wb[0][r * 264 + kb * 32 + q * 8]);
            const bf16x8_t Af1 = *reinterpret_cast<const bf16x8_t*>(
                &wb[1][r * 264 + kb * 32 + q * 8]);
            c0 = __builtin_amdgcn_mfma_f32_16x16x32_bf16(Af0, Bf, c0, 0, 0, 0);
            c1 = __builtin_amdgcn_mfma_f32_16x16x32_bf16(Af1, Bf, c1, 0, 0, 0);
        }
        if (r < 12) {
            const float b2 = npb2[r];
#pragma unroll
            for (int i = 0; i < 4; ++i)
                out[(n32 + q * 4 + i) * 12 + r] = c0[i] + b2;
#pragma unroll
            for (int i = 0; i < 4; ++i)
                out[(n32 + 16 + q * 4 + i) * 12 + r] = c1[i] + b2;
        }
    }
    __syncthreads();    // np L2 reads before pp L1 overwrites wb

    // ---- pp L1: z1p = silu(h@ppW1 + b1) -> wb stride 136
#pragma unroll
    for (int ct = 0; ct < 8; ++ct) {
        f32x4_t a0 = (f32x4_t){0.f, 0.f, 0.f, 0.f};
        f32x4_t a1 = (f32x4_t){0.f, 0.f, 0.f, 0.f};
#pragma unroll
        for (int kb = 0; kb < 4; ++kb) {
            const bf16x8_t Bf = *reinterpret_cast<const bf16x8_t*>(
                &wsb[PK_PPW1 + ((ct * 4 + kb) * 64 + lane) * 8]);
            a0 = __builtin_amdgcn_mfma_f32_16x16x32_bf16(Ah[0][kb], Bf, a0, 0, 0, 0);
            a1 = __builtin_amdgcn_mfma_f32_16x16x32_bf16(Ah[1][kb], Bf, a1, 0, 0, 0);
        }
        const int col = ct * 16 + r;
        const float b1 = ppb1[col];
#pragma unroll
        for (int i = 0; i < 4; ++i)
            wb[0][(q * 4 + i) * 136 + col] = __float2bfloat16(silu_f(a0[i] + b1));
#pragma unroll
        for (int i = 0; i < 4; ++i)
            wb[1][(q * 4 + i) * 136 + col] = __float2bfloat16(silu_f(a1[i] + b1));
    }
    __syncthreads();    // z1p writes before pp L2 frag reads

    // ---- pp L2: out3 = z1p @ ppW2 + b2
    {
        f32x4_t c0 = (f32x4_t){0.f, 0.f, 0.f, 0.f};
        f32x4_t c1 = (f32x4_t){0.f, 0.f, 0.f, 0.f};
#pragma unroll
        for (int kb = 0; kb < 4; ++kb) {
            const bf16x8_t Bf = *reinterpret_cast<const bf16x8_t*>(
                &wsb[PK_PPW2 + (kb * 64 + lane) * 8]);
            const bf16x8_t Af0 = *reinterpret_cast<const bf16x8_t*>(
                &wb[0][r * 136 + kb * 32 + q * 8]);
            const bf16x8_t Af1 = *reinterpret_cast<const bf16x8_t*>(
                &wb[1][r * 136 + kb * 32 + q * 8]);
            c0 = __builtin_amdgcn_mfma_f32_16x16x32_bf16(Af0, Bf, c0, 0, 0, 0);
            c1 = __builtin_amdgcn_mfma_f32_16x16x32_bf16(Af1, Bf, c1, 0, 0, 0);
        }
        if (r < 3) {
            const float b2 = ppb2[r];
#pragma unroll
            for (int i = 0; i < 4; ++i)
                out[NN * 12 + (n32 + q * 4 + i) * 3 + r] = c0[i] + b2;
#pragma unroll
            for (int i = 0; i < 4; ++i)
                out[NN * 12 + (n32 + 16 + q * 4 + i) * 3 + r] = c1[i] + b2;
        }
    }
}

// ---------------------------------------------------------------------------
extern "C" void kernel_launch(void* const* d_in, const int* in_sizes, int n_in,
                              void* d_out, int out_size, void* d_ws, size_t ws_size,
                              hipStream_t stream) {
    const float* x      = (const float*)d_in[0];
    const float* t      = (const float*)d_in[4];
    const float* topo   = (const float*)d_in[5];
    const float* stab   = (const float*)d_in[6];
    const float* sust   = (const float*)d_in[7];
    const int*   batch  = (const int*)d_in[8];
    const float* Wn     = (const float*)d_in[9];
    const float* bn     = (const float*)d_in[10];
    const float* tmW1   = (const float*)d_in[13];
    const float* tmb1   = (const float*)d_in[14];
    const float* tmW2   = (const float*)d_in[15];
    const float* tmb2   = (const float*)d_in[16];
    const float* topoW1 = (const float*)d_in[17];
    const float* topob1 = (const float*)d_in[18];
    const float* topoW2 = (const float*)d_in[19];
    const float* topob2 = (const float*)d_in[20];
    const float* stabW1 = (const float*)d_in[21];
    const float* stabb1 = (const float*)d_in[22];
    const float* stabW2 = (const float*)d_in[23];
    const float* stabb2 = (const float*)d_in[24];
    const float* sustW1 = (const float*)d_in[25];
    const float* sustb1 = (const float*)d_in[26];
    const float* sustW2 = (const float*)d_in[27];
    const float* sustb2 = (const float*)d_in[28];
    const float* combW1 = (const float*)d_in[29];
    const float* combb1 = (const float*)d_in[30];
    const float* combW2 = (const float*)d_in[31];
    const float* combb2 = (const float*)d_in[32];
    const float* Wv     = (const float*)d_in[35];
    const float* Wo     = (const float*)d_in[36];
    const float* bo     = (const float*)d_in[37];
    const float* npW1   = (const float*)d_in[44];
    const float* npb1   = (const float*)d_in[45];
    const float* npW2   = (const float*)d_in[46];
    const float* npb2   = (const float*)d_in[47];
    const float* ppW1   = (const float*)d_in[48];
    const float* ppb1   = (const float*)d_in[49];
    const float* ppW2   = (const float*)d_in[50];
    const float* ppb2   = (const float*)d_in[51];

    hbf16* wsb = (hbf16*)d_ws;
    float* gadd = (float*)(wsb + GADD_OFF);
    float* out = (float*)d_out;

    prep_kernel<<<GG + 116, 512, 0, stream>>>(
        t, topo, stab, sust,
        tmW1, tmb1, tmW2, tmb2,
        topoW1, topob1, topoW2, topob2,
        stabW1, stabb1, stabW2, stabb2,
        sustW1, sustb1, sustW2, sustb2,
        combW1, combb1, combW2, combb2,
        Wv, Wo, bo,
        npW1, npW2, ppW1, ppW2, Wn,
        gadd, wsb);

    node_kernel<<<NN / 32, 64, 0, stream>>>(
        x, batch, bn, npb1, npb2, ppb1, ppb2, gadd, wsb, out);
}

// Round 3
// 186.923 us; speedup vs baseline: 1.0295x; 1.0295x over previous
//
#include <hip/hip_runtime.h>
#include <hip/hip_bf16.h>

#define NN 20000
#define GG 128

typedef __bf16 bf16x8_t __attribute__((ext_vector_type(8)));
typedef float  f32x4_t  __attribute__((ext_vector_type(4)));
typedef __hip_bfloat16 hbf16;

// packed-weight table in ws (bf16-element offsets)
#define PK_NPW1 0       // 32768 : npW1 B-frags (16 ct x 4 kb x 64 lane x 8)
#define PK_PPW1 32768   // 16384 : ppW1 (8 ct x 4 kb x 64 x 8)
#define PK_NPW2 49152   //  4096 : npW2 (8 kb x 64 x 8), cols>=12 zero
#define PK_PPW2 53248   //  2048 : ppW2 (4 kb x 64 x 8), cols>=3 zero
#define PK_WN   55296   //  4096 : Wn   (8 ct x 64 x 8), K padded 12->32
#define GADD_OFF 59392  // then gadd fp32[128][128]

__device__ __forceinline__ float silu_f(float v) {
    return v * __builtin_amdgcn_rcpf(1.0f + __expf(-v));
}

// ---------------------------------------------------------------------------
// Kernel 1: blocks [0,128): per-graph gadd pipeline (512 thr, deep split-k).
//           blocks [128,244): pack weights into MFMA B-fragment order.
// (unchanged from verified version)
// ---------------------------------------------------------------------------
__global__ __launch_bounds__(512) void prep_kernel(
        const float* __restrict__ t, const float* __restrict__ topo,
        const float* __restrict__ stab, const float* __restrict__ sust,
        const float* __restrict__ tmW1, const float* __restrict__ tmb1,
        const float* __restrict__ tmW2, const float* __restrict__ tmb2,
        const float* __restrict__ topoW1, const float* __restrict__ topob1,
        const float* __restrict__ topoW2, const float* __restrict__ topob2,
        const float* __restrict__ stabW1, const float* __restrict__ stabb1,
        const float* __restrict__ stabW2, const float* __restrict__ stabb2,
        const float* __restrict__ sustW1, const float* __restrict__ sustb1,
        const float* __restrict__ sustW2, const float* __restrict__ sustb2,
        const float* __restrict__ combW1, const float* __restrict__ combb1,
        const float* __restrict__ combW2, const float* __restrict__ combb2,
        const float* __restrict__ Wv, const float* __restrict__ Wo,
        const float* __restrict__ bo,
        const float* __restrict__ npW1, const float* __restrict__ npW2,
        const float* __restrict__ ppW1, const float* __restrict__ ppW2,
        const float* __restrict__ Wn,
        float* __restrict__ gadd, hbf16* __restrict__ wsb) {
    const int tid = threadIdx.x;

    if (blockIdx.x >= GG) {
        const int s = (blockIdx.x - GG) * 512 + tid;
        if (s < 32768) {                       // npW1: [128,256]
            const int p = s;
            const int j = p & 7, l = (p >> 3) & 63, kb = (p >> 9) & 3, ct = p >> 11;
            const int k = kb * 32 + ((l >> 4) << 3) + j;
            const int n = ct * 16 + (l & 15);
            wsb[PK_NPW1 + p] = __float2bfloat16(npW1[k * 256 + n]);
        } else if (s < 49152) {                // ppW1: [128,128]
            const int p = s - 32768;
            const int j = p & 7, l = (p >> 3) & 63, kb = (p >> 9) & 3, ct = p >> 11;
            const int k = kb * 32 + ((l >> 4) << 3) + j;
            const int n = ct * 16 + (l & 15);
            wsb[PK_PPW1 + p] = __float2bfloat16(ppW1[k * 128 + n]);
        } else if (s < 53248) {                // npW2: [256,12] -> N padded 16
            const int p = s - 49152;
            const int j = p & 7, l = (p >> 3) & 63, kb = p >> 9;
            const int k = kb * 32 + ((l >> 4) << 3) + j;
            const int n = l & 15;
            wsb[PK_NPW2 + p] = __float2bfloat16(n < 12 ? npW2[k * 12 + n] : 0.0f);
        } else if (s < 55296) {                // ppW2: [128,3] -> N padded 16
            const int p = s - 53248;
            const int j = p & 7, l = (p >> 3) & 63, kb = p >> 9;
            const int k = kb * 32 + ((l >> 4) << 3) + j;
            const int n = l & 15;
            wsb[PK_PPW2 + p] = __float2bfloat16(n < 3 ? ppW2[k * 3 + n] : 0.0f);
        } else if (s < 59392) {                // Wn: [12,128] -> K padded 32
            const int p = s - 55296;
            const int j = p & 7, l = (p >> 3) & 63, ct = p >> 9;
            const int k = ((l >> 4) << 3) + j;
            const int n = ct * 16 + (l & 15);
            wsb[PK_WN + p] = __float2bfloat16(k < 12 ? Wn[k * 128 + n] : 0.0f);
        }
        return;
    }

    __shared__ float s_te[128];
    __shared__ float s_th1[256];
    __shared__ float s_tef[128];
    __shared__ float s_l1[64];
    __shared__ float s_cat[64];
    __shared__ float s_c1[64];
    __shared__ float s_cond[64];
    __shared__ float s_v[128];
    __shared__ float s_red[512];

    const int g = blockIdx.x;

    if (tid < 128) {
        const float tval = t[g];
        const int i = tid & 63;
        const float fr = __expf(-(float)i * 0.14619587892025688f);
        const float arg = tval * fr;
        s_te[tid] = (tid < 64) ? sinf(arg) : cosf(arg);
    } else if (tid < 192) {
        const int c = tid - 128;
        if (c < 32) {
            float acc = topob1[c];
            for (int k = 0; k < 7; ++k)
                acc += topo[g * 7 + k] * topoW1[k * 32 + c];
            s_l1[c] = silu_f(acc);
        } else if (c < 48) {
            const int j = c - 32;
            float acc = stabb1[j];
            for (int k = 0; k < 2; ++k)
                acc += stab[g * 2 + k] * stabW1[k * 16 + j];
            s_l1[c] = silu_f(acc);
        } else {
            const int j = c - 48;
            float acc = sustb1[j];
            for (int k = 0; k < 3; ++k)
                acc += sust[g * 3 + k] * sustW1[k * 16 + j];
            s_l1[c] = silu_f(acc);
        }
    }
    __syncthreads();

    // tmW1 [128]->[256]: split-k 2
    {
        const int col = tid & 255, half = tid >> 8;
        float acc = 0.0f;
#pragma unroll 32
        for (int kk = 0; kk < 64; ++kk) {
            const int k = half * 64 + kk;
            acc += s_te[k] * tmW1[k * 256 + col];
        }
        s_red[half * 256 + col] = acc;
    }
    __syncthreads();
    if (tid < 256)
        s_th1[tid] = silu_f(tmb1[tid] + s_red[tid] + s_red[256 + tid]);
    __syncthreads();

    // tmW2 [256]->[128]: split-k 4
    {
        const int col = tid & 127, qt = tid >> 7;
        float acc = 0.0f;
#pragma unroll 32
        for (int kk = 0; kk < 64; ++kk) {
            const int k = qt * 64 + kk;
            acc += s_th1[k] * tmW2[k * 128 + col];
        }
        s_red[qt * 128 + col] = acc;
    }
    __syncthreads();
    if (tid < 128) {
        s_tef[tid] = tmb2[tid] + s_red[tid] + s_red[128 + tid] +
                     s_red[256 + tid] + s_red[384 + tid];
    } else if (tid < 192) {
        const int c = tid - 128;
        if (c < 32) {
            float acc = topob2[c];
            for (int k = 0; k < 32; ++k)
                acc += s_l1[k] * topoW2[k * 32 + c];
            s_cat[c] = acc;
        } else if (c < 48) {
            const int j = c - 32;
            float acc = stabb2[j];
            for (int k = 0; k < 16; ++k)
                acc += s_l1[32 + k] * stabW2[k * 16 + j];
            s_cat[c] = acc;
        } else {
            const int j = c - 48;
            float acc = sustb2[j];
            for (int k = 0; k < 16; ++k)
                acc += s_l1[48 + k] * sustW2[k * 16 + j];
            s_cat[c] = acc;
        }
    }
    __syncthreads();

    // comb L1: split-k 8
    {
        const int col = tid & 63, part = tid >> 6;
        float acc = 0.0f;
#pragma unroll
        for (int kk = 0; kk < 8; ++kk) {
            const int k = part * 8 + kk;
            acc += s_cat[k] * combW1[k * 64 + col];
        }
        s_red[part * 64 + col] = acc;
    }
    __syncthreads();
    if (tid < 64) {
        float a = combb1[tid];
#pragma unroll
        for (int p = 0; p < 8; ++p) a += s_red[p * 64 + tid];
        s_c1[tid] = silu_f(a);
    }
    __syncthreads();

    // comb L2: split-k 8
    {
        const int col = tid & 63, part = tid >> 6;
        float acc = 0.0f;
#pragma unroll
        for (int kk = 0; kk < 8; ++kk) {
            const int k = part * 8 + kk;
            acc += s_c1[k] * combW2[k * 64 + col];
        }
        s_red[part * 64 + col] = acc;
    }
    __syncthreads();
    if (tid < 64) {
        float a = combb2[tid];
#pragma unroll
        for (int p = 0; p < 8; ++p) a += s_red[p * 64 + tid];
        s_cond[tid] = a;
    }
    __syncthreads();

    // v = cond @ Wv: split-k 4
    {
        const int col = tid & 127, qt = tid >> 7;
        float acc = 0.0f;
#pragma unroll
        for (int kk = 0; kk < 16; ++kk) {
            const int k = qt * 16 + kk;
            acc += s_cond[k] * Wv[k * 128 + col];
        }
        s_red[qt * 128 + col] = acc;
    }
    __syncthreads();
    if (tid < 128)
        s_v[tid] = s_red[tid] + s_red[128 + tid] + s_red[256 + tid] + s_red[384 + tid];
    __syncthreads();

    // a = v @ Wo: split-k 4 ; gadd = 6*(a + bo + silu(tef))
    {
        const int col = tid & 127, qt = tid >> 7;
        float acc = 0.0f;
#pragma unroll 32
        for (int kk = 0; kk < 32; ++kk) {
            const int k = qt * 32 + kk;
            acc += s_v[k] * Wo[k * 128 + col];
        }
        s_red[qt * 128 + col] = acc;
    }
    __syncthreads();
    if (tid < 128)
        gadd[g * 128 + tid] = 6.0f * (bo[tid] + s_red[tid] + s_red[128 + tid] +
                                      s_red[256 + tid] + s_red[384 + tid] +
                                      silu_f(s_tef[tid]));
}

// ---------------------------------------------------------------------------
// Kernel 2: per-node MLPs.  One wave per block, 16 nodes per wave
// (20000 = 1250 * 16 exactly, no tail).  B-fragments are read DIRECTLY from
// the packed global table (L2-resident, 1 KB coalesced per frag load) — no
// LDS weight staging, no cross-wave sharing, no weight barriers.
// NOTE (R2 post-mortem): 32 nodes/wave with shared B-frag loads REGRESSED
// (+4 µs) — halved block count (625 vs 1250) cut the TLP that hides the
// ~200 cy L2 fragment-load latency; the kernel is latency-bound, not
// L2-BW-bound, so the traffic halving bought nothing.  1250 one-wave
// blocks (~5/CU) is the measured-best configuration.
// MFMA contract (16x16x32 bf16), q=lane>>4, r=lane&15:
//   A[m=r][k=q*8+j]   B[k=q*8+j][n=r]   D[m=q*4+i][n=r]
// ---------------------------------------------------------------------------
__global__ __launch_bounds__(64) void node_kernel(
        const float* __restrict__ x, const int* __restrict__ batch,
        const float* __restrict__ bn,
        const float* __restrict__ npb1, const float* __restrict__ npb2,
        const float* __restrict__ ppb1, const float* __restrict__ ppb2,
        const float* __restrict__ gadd, const hbf16* __restrict__ wsb,
        float* __restrict__ out) {
    __shared__ __align__(16) hbf16 wb[16 * 264];   // 8.25 KB, single wave

    const int lane = threadIdx.x;
    const int q    = lane >> 4;
    const int r    = lane & 15;
    const int n16  = blockIdx.x * 16;

    // x A-frag (M=16, K=12 padded to 32)
    bf16x8_t Ax;
    {
        const int node = n16 + r;              // always < NN (exact tiling)
        float xv[8];
#pragma unroll
        for (int j = 0; j < 8; ++j) xv[j] = 0.0f;
        if (q == 0) {
            const float4 a = *reinterpret_cast<const float4*>(x + node * 12);
            const float4 b = *reinterpret_cast<const float4*>(x + node * 12 + 4);
            xv[0] = a.x; xv[1] = a.y; xv[2] = a.z; xv[3] = a.w;
            xv[4] = b.x; xv[5] = b.y; xv[6] = b.z; xv[7] = b.w;
        } else if (q == 1) {
            const float4 a = *reinterpret_cast<const float4*>(x + node * 12 + 8);
            xv[0] = a.x; xv[1] = a.y; xv[2] = a.z; xv[3] = a.w;
        }
#pragma unroll
        for (int j = 0; j < 8; ++j) {
            const hbf16 tv = __float2bfloat16(xv[j]);
            Ax[j] = *reinterpret_cast<const __bf16*>(&tv);
        }
    }
    // graph id per output row (D rows m = q*4+i)
    int gb[4];
#pragma unroll
    for (int i = 0; i < 4; ++i)
        gb[i] = batch[n16 + q * 4 + i];

    // ---- h = x@Wn + bn + gadd  -> wb stride 136 ; Ah regs
    bf16x8_t Ah[4];
    {
        f32x4_t hacc[8];
#pragma unroll
        for (int ct = 0; ct < 8; ++ct) {
            const bf16x8_t Bf = *reinterpret_cast<const bf16x8_t*>(
                &wsb[PK_WN + (ct * 64 + lane) * 8]);
            hacc[ct] = __builtin_amdgcn_mfma_f32_16x16x32_bf16(
                Ax, Bf, (f32x4_t){0.f, 0.f, 0.f, 0.f}, 0, 0, 0);
        }
#pragma unroll
        for (int ct = 0; ct < 8; ++ct) {
            const int n = ct * 16 + r;
            const float bv = bn[n];
#pragma unroll
            for (int i = 0; i < 4; ++i)
                wb[(q * 4 + i) * 136 + n] = __float2bfloat16(
                    hacc[ct][i] + bv + gadd[gb[i] * 128 + n]);
        }
    }
    __syncthreads();    // order h writes (all lanes) before Ah frag reads
    {
#pragma unroll
        for (int kb = 0; kb < 4; ++kb)
            Ah[kb] = *reinterpret_cast<const bf16x8_t*>(
                &wb[r * 136 + kb * 32 + q * 8]);
    }

    // ---- np L1: z1 = silu(h@npW1 + b1) -> wb stride 264  (K=256)
#pragma unroll
    for (int ct = 0; ct < 16; ++ct) {
        f32x4_t acc = (f32x4_t){0.f, 0.f, 0.f, 0.f};
#pragma unroll
        for (int kb = 0; kb < 4; ++kb) {
            const bf16x8_t Bf = *reinterpret_cast<const bf16x8_t*>(
                &wsb[PK_NPW1 + ((ct * 4 + kb) * 64 + lane) * 8]);
            acc = __builtin_amdgcn_mfma_f32_16x16x32_bf16(Ah[kb], Bf, acc, 0, 0, 0);
        }
        const int col = ct * 16 + r;
        const float b1 = npb1[col];
#pragma unroll
        for (int i = 0; i < 4; ++i)
            wb[(q * 4 + i) * 264 + col] = __float2bfloat16(silu_f(acc[i] + b1));
    }
    __syncthreads();    // z1 writes before np L2 frag reads

    // ---- np L2: out12 = z1 @ npW2 + b2
    {
        f32x4_t acc2 = (f32x4_t){0.f, 0.f, 0.f, 0.f};
#pragma unroll
        for (int kb = 0; kb < 8; ++kb) {
            const bf16x8_t Af = *reinterpret_cast<const bf16x8_t*>(
                &wb[r * 264 + kb * 32 + q * 8]);
            const bf16x8_t Bf = *reinterpret_cast<const bf16x8_t*>(
                &wsb[PK_NPW2 + (kb * 64 + lane) * 8]);
            acc2 = __builtin_amdgcn_mfma_f32_16x16x32_bf16(Af, Bf, acc2, 0, 0, 0);
        }
        if (r < 12) {
            const float b2 = npb2[r];
#pragma unroll
            for (int i = 0; i < 4; ++i)
                out[(n16 + q * 4 + i) * 12 + r] = acc2[i] + b2;
        }
    }
    __syncthreads();    // np L2 reads before pp L1 overwrites wb

    // ---- pp L1: z1p = silu(h@ppW1 + b1) -> wb stride 136
#pragma unroll
    for (int ct = 0; ct < 8; ++ct) {
        f32x4_t acc = (f32x4_t){0.f, 0.f, 0.f, 0.f};
#pragma unroll
        for (int kb = 0; kb < 4; ++kb) {
            const bf16x8_t Bf = *reinterpret_cast<const bf16x8_t*>(
                &wsb[PK_PPW1 + ((ct * 4 + kb) * 64 + lane) * 8]);
            acc = __builtin_amdgcn_mfma_f32_16x16x32_bf16(Ah[kb], Bf, acc, 0, 0, 0);
        }
        const int col = ct * 16 + r;
        const float b1 = ppb1[col];
#pragma unroll
        for (int i = 0; i < 4; ++i)
            wb[(q * 4 + i) * 136 + col] = __float2bfloat16(silu_f(acc[i] + b1));
    }
    __syncthreads();    // z1p writes before pp L2 frag reads

    // ---- pp L2: out3 = z1p @ ppW2 + b2
    {
        f32x4_t acc2 = (f32x4_t){0.f, 0.f, 0.f, 0.f};
#pragma unroll
        for (int kb = 0; kb < 4; ++kb) {
            const bf16x8_t Af = *reinterpret_cast<const bf16x8_t*>(
                &wb[r * 136 + kb * 32 + q * 8]);
            const bf16x8_t Bf = *reinterpret_cast<const bf16x8_t*>(
                &wsb[PK_PPW2 + (kb * 64 + lane) * 8]);
            acc2 = __builtin_amdgcn_mfma_f32_16x16x32_bf16(Af, Bf, acc2, 0, 0, 0);
        }
        if (r < 3) {
            const float b2 = ppb2[r];
#pragma unroll
            for (int i = 0; i < 4; ++i)
                out[NN * 12 + (n16 + q * 4 + i) * 3 + r] = acc2[i] + b2;
        }
    }
}

// ---------------------------------------------------------------------------
extern "C" void kernel_launch(void* const* d_in, const int* in_sizes, int n_in,
                              void* d_out, int out_size, void* d_ws, size_t ws_size,
                              hipStream_t stream) {
    const float* x      = (const float*)d_in[0];
    const float* t      = (const float*)d_in[4];
    const float* topo   = (const float*)d_in[5];
    const float* stab   = (const float*)d_in[6];
    const float* sust   = (const float*)d_in[7];
    const int*   batch  = (const int*)d_in[8];
    const float* Wn     = (const float*)d_in[9];
    const float* bn     = (const float*)d_in[10];
    const float* tmW1   = (const float*)d_in[13];
    const float* tmb1   = (const float*)d_in[14];
    const float* tmW2   = (const float*)d_in[15];
    const float* tmb2   = (const float*)d_in[16];
    const float* topoW1 = (const float*)d_in[17];
    const float* topob1 = (const float*)d_in[18];
    const float* topoW2 = (const float*)d_in[19];
    const float* topob2 = (const float*)d_in[20];
    const float* stabW1 = (const float*)d_in[21];
    const float* stabb1 = (const float*)d_in[22];
    const float* stabW2 = (const float*)d_in[23];
    const float* stabb2 = (const float*)d_in[24];
    const float* sustW1 = (const float*)d_in[25];
    const float* sustb1 = (const float*)d_in[26];
    const float* sustW2 = (const float*)d_in[27];
    const float* sustb2 = (const float*)d_in[28];
    const float* combW1 = (const float*)d_in[29];
    const float* combb1 = (const float*)d_in[30];
    const float* combW2 = (const float*)d_in[31];
    const float* combb2 = (const float*)d_in[32];
    const float* Wv     = (const float*)d_in[35];
    const float* Wo     = (const float*)d_in[36];
    const float* bo     = (const float*)d_in[37];
    const float* npW1   = (const float*)d_in[44];
    const float* npb1   = (const float*)d_in[45];
    const float* npW2   = (const float*)d_in[46];
    const float* npb2   = (const float*)d_in[47];
    const float* ppW1   = (const float*)d_in[48];
    const float* ppb1   = (const float*)d_in[49];
    const float* ppW2   = (const float*)d_in[50];
    const float* ppb2   = (const float*)d_in[51];

    hbf16* wsb = (hbf16*)d_ws;
    float* gadd = (float*)(wsb + GADD_OFF);
    float* out = (float*)d_out;

    prep_kernel<<<GG + 116, 512, 0, stream>>>(
        t, topo, stab, sust,
        tmW1, tmb1, tmW2, tmb2,
        topoW1, topob1, topoW2, topob2,
        stabW1, stabb1, stabW2, stabb2,
        sustW1, sustb1, sustW2, sustb2,
        combW1, combb1, combW2, combb2,
        Wv, Wo, bo,
        npW1, npW2, ppW1, ppW2, Wn,
        gadd, wsb);

    node_kernel<<<NN / 16, 64, 0, stream>>>(
        x, batch, bn, npb1, npb2, ppb1, ppb2, gadd, wsb, out);
}